// Round 1
// baseline (2361.348 us; speedup 1.0000x reference)
//
#include <hip/hip_runtime.h>

typedef __attribute__((ext_vector_type(8))) short bf16x8;
typedef __attribute__((ext_vector_type(4))) float f32x4;
typedef unsigned short u16;
typedef unsigned int u32;

__device__ __forceinline__ u16 f2bf(float f){
  u32 u = __float_as_uint(f);
  return (u16)((u + 0x7FFFu + ((u >> 16) & 1u)) >> 16);
}

// ---- Kernel 1: weights fp32 -> bf16; q rows (first 256) pre-scaled by 1/sqrt(32) ----
__global__ __launch_bounds__(256) void convert_w(
    const float* __restrict__ q0, const float* __restrict__ o0,
    const float* __restrict__ q1, const float* __restrict__ o1,
    const float* __restrict__ q2, const float* __restrict__ o2,
    u16* __restrict__ dst){
  const int axis = blockIdx.y;
  const float* qw = (axis == 0) ? q0 : ((axis == 1) ? q1 : q2);
  const float* ow = (axis == 0) ? o0 : ((axis == 1) ? o1 : o2);
  const int i = blockIdx.x * 256 + threadIdx.x;
  float v;
  if (i < 196608){
    v = qw[i];
    if (i < 65536) v *= 0.17677669529663687f;   // rows 0..255 = Wq
  } else {
    v = ow[i - 196608];
  }
  dst[(size_t)axis * 262144 + i] = f2bf(v);
}

// ---- Kernel 2: (b,c,p) -> (b,p,c) channels-last transpose ----
__global__ __launch_bounds__(256) void transpose_in(
    const float* __restrict__ x, float* __restrict__ xt){
  __shared__ float tile[64][65];
  const int tx = threadIdx.x & 63, ty = threadIdx.x >> 6;
  const size_t p0 = (size_t)blockIdx.x * 64;
  const int c0 = blockIdx.y * 64;
  const size_t b = blockIdx.z;
  const float* src = x + (b * 256 + c0) * 110592 + p0;
  #pragma unroll
  for (int i = 0; i < 16; ++i){
    const int rr = ty * 16 + i;
    tile[rr][tx] = src[(size_t)rr * 110592 + tx];
  }
  __syncthreads();
  float* dstp = xt + (b * 110592 + p0) * 256 + c0;
  #pragma unroll
  for (int i = 0; i < 16; ++i){
    const int rr = ty * 16 + i;
    dstp[(size_t)rr * 256 + tx] = tile[tx][rr];
  }
}

// ---- Kernel 3: one axial pass. Block = one sequence (48 tokens x 256 ch), 4 waves. ----
// LDS map (125952 B total):
//   XLN  @ 0      : bf16 [48][256], rows 512B, col-byte XOR ((row&7)<<4)
//   O    @ 24576  : bf16 [48][256], same swizzle
//   per-wave scratch @ 49152 + wv*19200:
//     Q @+0 [48][40]bf16, K @+3840 [48][40]bf16, VT @+7680 [32][72]bf16, P @+12288 [48][72]bf16
//   PROJ @ 49152  : f32 [48][260]  (aliases wave scratch; used after barrier)
#define SMEM_BYTES 125952

__launch_bounds__(256, 1)
__global__ void axial_pass(const float* xt, float* dst,
                           const u16* __restrict__ wbf,
                           const float* __restrict__ bqkv,
                           const float* __restrict__ bo,
                           const float* __restrict__ lnw,
                           const float* __restrict__ lnb,
                           const float* __restrict__ gammap,
                           const int axis){
  extern __shared__ char smem[];
  const int tid = threadIdx.x;
  const int wv = tid >> 6;
  const int ln = tid & 63;
  const int col = ln & 15;
  const int g = ln >> 4;

  const int s = blockIdx.x;
  const int bb = s / 2304;
  const int r2 = s - bb * 2304;
  const int i1 = r2 / 48;
  const int i2 = r2 - i1 * 48;
  size_t base; size_t tstride;
  if (axis == 0){ base = ((size_t)bb * 110592 + i1 * 48 + i2) * 256; tstride = 589824; }
  else if (axis == 1){ base = ((size_t)bb * 110592 + i1 * 2304 + i2) * 256; tstride = 12288; }
  else { base = ((size_t)bb * 110592 + i1 * 2304 + i2 * 48) * 256; tstride = 256; }

  const float gamma = gammap[0];
  const f32x4 zf = {0.f, 0.f, 0.f, 0.f};

  // ---- Phase A: LN (fp32) -> x_ln bf16 in LDS ----
  {
    const float4 lw = *(const float4*)(lnw + ln * 4);
    const float4 lb = *(const float4*)(lnb + ln * 4);
    for (int t = wv; t < 48; t += 4){
      const float4 v = *(const float4*)(xt + base + (size_t)t * tstride + ln * 4);
      float sum = v.x + v.y + v.z + v.w;
      float sq = v.x * v.x + v.y * v.y + v.z * v.z + v.w * v.w;
      #pragma unroll
      for (int m = 1; m < 64; m <<= 1){
        sum += __shfl_xor(sum, m, 64);
        sq  += __shfl_xor(sq, m, 64);
      }
      const float mu = sum * (1.0f / 256.0f);
      const float var = sq * (1.0f / 256.0f) - mu * mu;
      const float rstd = rsqrtf(var + 1e-5f);
      const u16 h0 = f2bf((v.x - mu) * rstd * lw.x + lb.x);
      const u16 h1 = f2bf((v.y - mu) * rstd * lw.y + lb.y);
      const u16 h2 = f2bf((v.z - mu) * rstd * lw.z + lb.z);
      const u16 h3 = f2bf((v.w - mu) * rstd * lw.w + lb.w);
      uint2 pk;
      pk.x = (u32)h0 | ((u32)h1 << 16);
      pk.y = (u32)h2 | ((u32)h3 << 16);
      *(uint2*)(smem + t * 512 + ((ln * 8) ^ ((t & 7) << 4))) = pk;
    }
  }

  char* wvs = smem + 49152 + wv * 19200;
  // zero K-padding of VT (token cols 48..63) and P (cols 48..63) once; never written with data
  for (int i = ln; i < 512; i += 64){
    *(u16*)(wvs + 7680 + (i >> 4) * 144 + (48 + (i & 15)) * 2) = 0;
  }
  for (int i = ln; i < 768; i += 64){
    *(u16*)(wvs + 12288 + (i >> 4) * 144 + (48 + (i & 15)) * 2) = 0;
  }
  __syncthreads();

  // ---- Phase B: each wave handles heads 2*wv and 2*wv+1 ----
  for (int hh = 0; hh < 2; ++hh){
    const int h = wv * 2 + hh;

    // QKV GEMM: 48x(32+32+32) = x_ln(48x256) @ W^T, K=256
    f32x4 aq[3][2], ak[3][2], av[3][2];
    #pragma unroll
    for (int mt = 0; mt < 3; ++mt)
      #pragma unroll
      for (int nt = 0; nt < 2; ++nt){ aq[mt][nt] = zf; ak[mt][nt] = zf; av[mt][nt] = zf; }

    #pragma unroll
    for (int ks = 0; ks < 8; ++ks){
      bf16x8 a[3];
      #pragma unroll
      for (int mt = 0; mt < 3; ++mt){
        const int rr = mt * 16 + col;
        a[mt] = *(const bf16x8*)(smem + rr * 512 + ((ks * 64 + g * 16) ^ ((rr & 7) << 4)));
      }
      const int wc = ks * 32 + g * 8;
      #pragma unroll
      for (int nt = 0; nt < 2; ++nt){
        const int rq = h * 32 + nt * 16 + col;
        const bf16x8 bq = *(const bf16x8*)(wbf + (size_t)rq * 256 + wc);
        const bf16x8 bk = *(const bf16x8*)(wbf + (size_t)(rq + 256) * 256 + wc);
        const bf16x8 bv = *(const bf16x8*)(wbf + (size_t)(rq + 512) * 256 + wc);
        #pragma unroll
        for (int mt = 0; mt < 3; ++mt){
          aq[mt][nt] = __builtin_amdgcn_mfma_f32_16x16x32_bf16(a[mt], bq, aq[mt][nt], 0, 0, 0);
          ak[mt][nt] = __builtin_amdgcn_mfma_f32_16x16x32_bf16(a[mt], bk, ak[mt][nt], 0, 0, 0);
          av[mt][nt] = __builtin_amdgcn_mfma_f32_16x16x32_bf16(a[mt], bv, av[mt][nt], 0, 0, 0);
        }
      }
    }

    // store q,k (token-major [48][40]) and v^T ([32 hd][72 tok]) with bias
    #pragma unroll
    for (int nt = 0; nt < 2; ++nt){
      const int nloc = nt * 16 + col;
      const float bqv = bqkv[h * 32 + nloc] * 0.17677669529663687f;
      const float bkv = bqkv[256 + h * 32 + nloc];
      const float bvv = bqkv[512 + h * 32 + nloc];
      #pragma unroll
      for (int mt = 0; mt < 3; ++mt)
        #pragma unroll
        for (int i = 0; i < 4; ++i){
          const int rr = mt * 16 + g * 4 + i;
          *(u16*)(wvs + 0    + rr * 80 + nloc * 2) = f2bf(aq[mt][nt][i] + bqv);
          *(u16*)(wvs + 3840 + rr * 80 + nloc * 2) = f2bf(ak[mt][nt][i] + bkv);
          *(u16*)(wvs + 7680 + nloc * 144 + rr * 2) = f2bf(av[mt][nt][i] + bvv);
        }
    }

    // scores = q @ k^T (K = hd = 32: one MFMA per 16x16 tile)
    bf16x8 qa[3], kb[3];
    #pragma unroll
    for (int mt = 0; mt < 3; ++mt){
      const int rr = mt * 16 + col;
      qa[mt] = *(const bf16x8*)(wvs + 0    + rr * 80 + g * 16);
      kb[mt] = *(const bf16x8*)(wvs + 3840 + rr * 80 + g * 16);
    }
    f32x4 sc[3][3];
    #pragma unroll
    for (int mt = 0; mt < 3; ++mt)
      #pragma unroll
      for (int nt = 0; nt < 3; ++nt)
        sc[mt][nt] = __builtin_amdgcn_mfma_f32_16x16x32_bf16(qa[mt], kb[nt], zf, 0, 0, 0);

    // softmax over k-dim (row = q token lives across a 16-lane group) -> P bf16
    #pragma unroll
    for (int mt = 0; mt < 3; ++mt)
      #pragma unroll
      for (int i = 0; i < 4; ++i){
        const float s0 = sc[mt][0][i], s1 = sc[mt][1][i], s2 = sc[mt][2][i];
        float mx = fmaxf(fmaxf(s0, s1), s2);
        #pragma unroll
        for (int m = 1; m < 16; m <<= 1) mx = fmaxf(mx, __shfl_xor(mx, m, 64));
        const float e0 = __expf(s0 - mx), e1 = __expf(s1 - mx), e2 = __expf(s2 - mx);
        float sm = e0 + e1 + e2;
        #pragma unroll
        for (int m = 1; m < 16; m <<= 1) sm += __shfl_xor(sm, m, 64);
        const float inv = 1.0f / sm;
        const int rr = mt * 16 + g * 4 + i;
        *(u16*)(wvs + 12288 + rr * 144 + (col) * 2)      = f2bf(e0 * inv);
        *(u16*)(wvs + 12288 + rr * 144 + (16 + col) * 2) = f2bf(e1 * inv);
        *(u16*)(wvs + 12288 + rr * 144 + (32 + col) * 2) = f2bf(e2 * inv);
      }

    // PV: O_head(48x32) = P(48x48, zero-padded to 64) @ v; B = v^T
    f32x4 ov[3][2];
    #pragma unroll
    for (int mt = 0; mt < 3; ++mt)
      #pragma unroll
      for (int nt = 0; nt < 2; ++nt) ov[mt][nt] = zf;
    #pragma unroll
    for (int ks2 = 0; ks2 < 2; ++ks2){
      bf16x8 pa[3], vb[2];
      #pragma unroll
      for (int mt = 0; mt < 3; ++mt){
        const int rr = mt * 16 + col;
        pa[mt] = *(const bf16x8*)(wvs + 12288 + rr * 144 + ks2 * 64 + g * 16);
      }
      #pragma unroll
      for (int nt = 0; nt < 2; ++nt){
        const int nn = nt * 16 + col;
        vb[nt] = *(const bf16x8*)(wvs + 7680 + nn * 144 + ks2 * 64 + g * 16);
      }
      #pragma unroll
      for (int mt = 0; mt < 3; ++mt)
        #pragma unroll
        for (int nt = 0; nt < 2; ++nt)
          ov[mt][nt] = __builtin_amdgcn_mfma_f32_16x16x32_bf16(pa[mt], vb[nt], ov[mt][nt], 0, 0, 0);
    }

    // O store (shared, swizzled like x_ln)
    #pragma unroll
    for (int mt = 0; mt < 3; ++mt)
      #pragma unroll
      for (int nt = 0; nt < 2; ++nt)
        #pragma unroll
        for (int i = 0; i < 4; ++i){
          const int rr = mt * 16 + g * 4 + i;
          const int cc = h * 32 + nt * 16 + col;
          *(u16*)(smem + 24576 + rr * 512 + ((cc * 2) ^ ((rr & 7) << 4))) = f2bf(ov[mt][nt][i]);
        }
  }
  __syncthreads();

  // ---- Phase D: out projection: proj(48x256) = O(48x256) @ Wo^T; wave wv owns cols 64*wv.. ----
  f32x4 po[3][4];
  #pragma unroll
  for (int mt = 0; mt < 3; ++mt)
    #pragma unroll
    for (int nt = 0; nt < 4; ++nt) po[mt][nt] = zf;
  const u16* wo = wbf + 196608;
  #pragma unroll
  for (int ks = 0; ks < 8; ++ks){
    bf16x8 a[3];
    #pragma unroll
    for (int mt = 0; mt < 3; ++mt){
      const int rr = mt * 16 + col;
      a[mt] = *(const bf16x8*)(smem + 24576 + rr * 512 + ((ks * 64 + g * 16) ^ ((rr & 7) << 4)));
    }
    #pragma unroll
    for (int nt = 0; nt < 4; ++nt){
      const int rn = wv * 64 + nt * 16 + col;
      const bf16x8 b = *(const bf16x8*)(wo + (size_t)rn * 256 + ks * 32 + g * 8);
      #pragma unroll
      for (int mt = 0; mt < 3; ++mt)
        po[mt][nt] = __builtin_amdgcn_mfma_f32_16x16x32_bf16(a[mt], b, po[mt][nt], 0, 0, 0);
    }
  }
  // gamma*(proj+bias) -> PROJ f32 (scratch is dead for all waves after the barrier above)
  float* pl = (float*)(smem + 49152);
  #pragma unroll
  for (int nt = 0; nt < 4; ++nt){
    const int cc = wv * 64 + nt * 16 + col;
    const float bov = bo[cc];
    #pragma unroll
    for (int mt = 0; mt < 3; ++mt)
      #pragma unroll
      for (int i = 0; i < 4; ++i){
        const int rr = mt * 16 + g * 4 + i;
        pl[rr * 260 + cc] = gamma * (po[mt][nt][i] + bov);
      }
  }
  __syncthreads();

  // ---- Phase E: residual add + store. thread = channel c. ----
  const int c = tid;
  if (axis < 2){
    for (int t = 0; t < 48; ++t){
      const size_t idx = base + (size_t)t * tstride + c;
      dst[idx] = xt[idx] + pl[t * 260 + c];   // in-place: block owns these elements
    }
  } else {
    // fused transpose-out to (b,c,d,h,w); tokens are w -> contiguous
    float* op = dst + ((size_t)bb * 256 + c) * 110592 + (size_t)i1 * 2304 + i2 * 48;
    for (int tb = 0; tb < 12; ++tb){
      float4 o4;
      o4.x = xt[base + (size_t)(tb * 4 + 0) * 256 + c] + pl[(tb * 4 + 0) * 260 + c];
      o4.y = xt[base + (size_t)(tb * 4 + 1) * 256 + c] + pl[(tb * 4 + 1) * 260 + c];
      o4.z = xt[base + (size_t)(tb * 4 + 2) * 256 + c] + pl[(tb * 4 + 2) * 260 + c];
      o4.w = xt[base + (size_t)(tb * 4 + 3) * 256 + c] + pl[(tb * 4 + 3) * 260 + c];
      *(float4*)(op + tb * 4) = o4;
    }
  }
}

extern "C" void kernel_launch(void* const* d_in, const int* in_sizes, int n_in,
                              void* d_out, int out_size, void* d_ws, size_t ws_size,
                              hipStream_t stream){
  const float* x = (const float*)d_in[0];
  const float* gamma = (const float*)d_in[1];

  // ws layout: xt fp32 (56,623,104 floats) | weights bf16 (3 * 262,144)
  const size_t XT_ELEMS = 56623104;
  const size_t need = XT_ELEMS * 4 + (size_t)3 * 262144 * 2;
  if (ws_size < need) return;  // loud failure via wrong output rather than OOB write
  float* xt = (float*)d_ws;
  u16* wbf = (u16*)((char*)d_ws + XT_ELEMS * 4);

  hipFuncSetAttribute(reinterpret_cast<const void*>(axial_pass),
                      hipFuncAttributeMaxDynamicSharedMemorySize, SMEM_BYTES);

  convert_w<<<dim3(1024, 3), 256, 0, stream>>>(
      (const float*)d_in[4],  (const float*)d_in[6],
      (const float*)d_in[10], (const float*)d_in[12],
      (const float*)d_in[16], (const float*)d_in[18], wbf);

  transpose_in<<<dim3(1728, 4, 2), 256, 0, stream>>>(x, xt);

  for (int a = 0; a < 3; ++a){
    axial_pass<<<4608, 256, SMEM_BYTES, stream>>>(
        xt, (a == 2) ? (float*)d_out : xt,
        wbf + (size_t)a * 262144,
        (const float*)d_in[5 + 6 * a],   // bqkv
        (const float*)d_in[7 + 6 * a],   // bo
        (const float*)d_in[2 + 6 * a],   // ln w
        (const float*)d_in[3 + 6 * a],   // ln b
        gamma, a);
  }
}